// Round 8
// baseline (218.275 us; speedup 1.0000x reference)
//
#include <hip/hip_runtime.h>

constexpr int Lc = 16;
constexpr int Cc = 16;
constexpr int Hc = 128;
constexpr int Wc = 256;
constexpr float DECAYc = 0.1f;
constexpr int HWc = Hc * Wc;

// float -> bf16 bits, round-to-nearest-even (inputs are finite normals).
__device__ inline unsigned short f2bf(float f) {
    unsigned int u = __float_as_uint(f);
    u += 0x7fffu + ((u >> 16) & 1u);
    return (unsigned short)(u >> 16);
}
// packed uint (bf16 pair) -> 2 floats
__device__ inline float2 bf2f2(unsigned int u) {
    return make_float2(__uint_as_float(u << 16),
                       __uint_as_float(u & 0xffff0000u));
}

constexpr int topbit(unsigned m) { int r = 0; while (m >>= 1) ++r; return r; }

// ---------------------------------------------------------------------------
// Kernel 1: transpose+convert img (L,C,H,W) f32 -> imgTb (L,H,W,C) bf16.
// (unchanged)
// ---------------------------------------------------------------------------
__global__ __launch_bounds__(256) void transpose_cvt_bf16(
    const float* __restrict__ img, unsigned short* __restrict__ imgTb)
{
    const int tid = threadIdx.x;
    const int h2 = tid & 1;
    const int wq = tid >> 1;             // 0..127
    const int kf  = blockIdx.x >> 5;     // 0..15
    const int px0 = (blockIdx.x & 31) * 1024;
    const float* __restrict__ srcb = img + (size_t)kf * Cc * HWc + (size_t)(8 * h2) * HWc;
#pragma unroll
    for (int rr = 0; rr < 8; ++rr) {
        const int px = px0 + rr * 128 + wq;
        float v[8];
#pragma unroll
        for (int c = 0; c < 8; ++c) v[c] = srcb[c * HWc + px];
        uint4 o;
        o.x = (unsigned int)f2bf(v[0]) | ((unsigned int)f2bf(v[1]) << 16);
        o.y = (unsigned int)f2bf(v[2]) | ((unsigned int)f2bf(v[3]) << 16);
        o.z = (unsigned int)f2bf(v[4]) | ((unsigned int)f2bf(v[5]) << 16);
        o.w = (unsigned int)f2bf(v[6]) | ((unsigned int)f2bf(v[7]) << 16);
        *(uint4*)(imgTb + ((size_t)kf * HWc + px) * Cc + 8 * h2) = o;
    }
}

// ---------------------------------------------------------------------------
// Masked chunk (EXACT round-5 inner-loop structure: two j-compacted batches
// of <=2 active t, <=8 uint4 in flight -> bounded buffers, no spill; round 6
// proved a sparse [Lc]-indexed merged batch spills to scratch: WRITE +43MB).
// bk is pre-offset by the wave-uniform channel half (+16B for half 1), so a
// lane's gather is a single flat 16B load of its 8 channels.
// x-wrap folded into x0&255 / x1&255 (bit-exact, validated round 2).
// ---------------------------------------------------------------------------
template <unsigned MASK, int TLO, int THI>
__device__ __forceinline__ void do_chunk16(
    int k, const unsigned short* __restrict__ bk,
    const float* sx1, const float* sy1, float fxk, float fyk,
    const float* __restrict__ wtab, float (*acc)[8])
{
    constexpr int NT = THI - TLO + 1;
    int   offs[NT][4];
    float wts [NT][4];
    uint4 ld  [NT][4];

    // 1) coordinates + folded weights
#pragma unroll
    for (int t = TLO; t <= THI; ++t) {
        if (!((MASK >> t) & 1u)) continue;
        if (t > k) {
            const int j = t - TLO;
            const float wkt = wtab[t * Lc + k];
            const float ix = (sx1[t] - fxk) * (Wc * 0.5f) - 0.5f;
            const float iy = (sy1[t] - fyk) * (Hc * 0.5f) - 0.5f;
            const float x0f = floorf(ix);
            const float y0f = floorf(iy);
            const float wx = ix - x0f;
            const float wy = iy - y0f;
            const int x0 = (int)x0f;
            const int y0 = (int)y0f;
            const int x0r = x0 & (Wc - 1);
            const int x1r = (x0 + 1) & (Wc - 1);
            const int y0c = min(max(y0, 0), Hc - 1);
            const int y1c = min(max(y0 + 1, 0), Hc - 1);
            const float wb = wkt * wy;
            const float wa = wkt - wb;
            const float omx = 1.0f - wx;
            wts[j][0] = wa * omx;   // a00
            wts[j][1] = wa * wx;    // a10
            wts[j][2] = wb * omx;   // a01
            wts[j][3] = wb * wx;    // a11
            offs[j][0] = y0c * Wc + x0r;
            offs[j][1] = y0c * Wc + x1r;
            offs[j][2] = y1c * Wc + x0r;
            offs[j][3] = y1c * Wc + x1r;
        }
    }
    // 2) issue all loads (up to 8 uint4 in flight)
#pragma unroll
    for (int t = TLO; t <= THI; ++t) {
        if (!((MASK >> t) & 1u)) continue;
        if (t > k) {
            const int j = t - TLO;
#pragma unroll
            for (int n = 0; n < 4; ++n)
                ld[j][n] = *(const uint4*)(bk + (size_t)offs[j][n] * Cc);
        }
    }
    // 3) convert + accumulate (8 channels per lane)
#pragma unroll
    for (int t = TLO; t <= THI; ++t) {
        if (!((MASK >> t) & 1u)) continue;
        if (t > k) {
            const int j = t - TLO;
#pragma unroll
            for (int n = 0; n < 4; ++n) {
                const float a = wts[j][n];
                const float2 f01 = bf2f2(ld[j][n].x);
                const float2 f23 = bf2f2(ld[j][n].y);
                const float2 f45 = bf2f2(ld[j][n].z);
                const float2 f67 = bf2f2(ld[j][n].w);
                acc[t][0] += a * f01.x;
                acc[t][1] += a * f01.y;
                acc[t][2] += a * f23.x;
                acc[t][3] += a * f23.y;
                acc[t][4] += a * f45.x;
                acc[t][5] += a * f45.y;
                acc[t][6] += a * f67.x;
                acc[t][7] += a * f67.y;
            }
        }
    }
}

// ---------------------------------------------------------------------------
// One t-quarter (MASK) for one pixel lane (wave-uniform channel half).
// imgTbH points at imgTb + 16B*half; imgH/outH at img/out + 8*half planes.
// ---------------------------------------------------------------------------
template <unsigned MASK>
__device__ __forceinline__ void run_quarter(
    const unsigned short* __restrict__ imgTbH,
    const float* __restrict__ cum_flow,
    const float* __restrict__ imgH,
    float* __restrict__ outH,
    const float* wtab,
    int pix, float base_x, float base_y)
{
    constexpr unsigned LOOPM = MASK & ~1u;   // t=0 never samples (k<t empty)

    float sx1[Lc], sy1[Lc];
#pragma unroll
    for (int t = 0; t < Lc; ++t) {
        if (!((LOOPM >> t) & 1u)) continue;
        sx1[t] = base_x + cum_flow[(t * 2 + 0) * HWc + pix] + 1.0f;
        sy1[t] = base_y + cum_flow[(t * 2 + 1) * HWc + pix] + 1.0f;
    }

    float acc[Lc][8];
#pragma unroll
    for (int t = 0; t < Lc; ++t) {
        if (!((MASK >> t) & 1u)) continue;
#pragma unroll
        for (int c = 0; c < 8; ++c) acc[t][c] = 0.f;
    }

    constexpr int KMAX = topbit(MASK);   // highest masked t; k in [0, KMAX)
    for (int k = 0; k < KMAX; ++k) {
        const float fxk = cum_flow[(k * 2 + 0) * HWc + pix];
        const float fyk = cum_flow[(k * 2 + 1) * HWc + pix];
        const unsigned short* __restrict__ bk = imgTbH + (size_t)k * HWc * Cc;
        do_chunk16<LOOPM, 1, 7>(k, bk, sx1, sy1, fxk, fyk, wtab, acc);
        do_chunk16<LOOPM, 8, 15>(k, bk, sx1, sy1, fxk, fyk, wtab, acc);
    }

    // Epilogue: add exact fp32 identity sample (t==k, weight 1) and store.
    // 64 lanes x 4B contiguous per (t,c) plane = 256B clean segments.
#pragma unroll
    for (int t = 0; t < Lc; ++t) {
        if (!((MASK >> t) & 1u)) continue;
        const float* __restrict__ ip = imgH + (size_t)t * Cc * HWc + pix;
        float* __restrict__ op = outH + (size_t)t * Cc * HWc + pix;
#pragma unroll
        for (int c = 0; c < 8; ++c)
            op[c * HWc] = acc[t][c] + ip[c * HWc];
    }
}

// ---------------------------------------------------------------------------
// Kernel 2: round-5 structure with the 64-px-wave remap.
// Block = 64-px group x ONE channel half; 4 waves = 4 t-quarters
// {15,8,5,2} {14,9,6,1} {13,10,4,3} {12,11,7,0} (30 (k,t)-pairs each).
// vs round 5 (76us, 32px x 2-half lanes):
//  - coord math + flow reads computed ONCE per pixel, not twice (the two
//    half-lanes duplicated them) -> coord VALU and flow VMEM halved;
//  - per (t,c) plane a block/wave now covers 64 px = 256B: clean write
//    granule (R0: 64px -> WRITE==output 33MB; R3/R5: 32px -> 53MB;
//    R4: 16px -> 61MB) and clean identity reads;
//  - half comes from b>>9 -> wave-uniform, folded into base pointers;
//    both halves of a band share the XCD (512%8==0 keeps band=b&7) and
//    are co-resident (1024 blocks, 4/CU), so imgTb 128B lines fetched by
//    half-0 serve half-1 from L2.
// Inner loop EXACTLY round 5's (round 6's merged batch spilled to scratch).
// ---------------------------------------------------------------------------
__global__ __launch_bounds__(256, 4) void gridsample_bf16_q64(
    const unsigned short* __restrict__ imgTb,  // (L, H, W, C) bf16
    const float* __restrict__ cum_flow,        // (L, 2, H, W)
    const float* __restrict__ mask,            // (L, L)
    const float* __restrict__ decay,           // (L, L)
    const float* __restrict__ img,             // (L, C, H, W) f32, identity
    float* __restrict__ out)                   // (L, C, H, W)
{
    __shared__ float wtab[Lc * Lc];
    const int tid = threadIdx.x;
    if (tid < Lc * Lc)
        wtab[tid] = mask[tid] * __expf(-DECAYc * decay[tid]);
    __syncthreads();

    const int lane = tid & 63;           // pixel within 64-px group
    const int wv   = tid >> 6;           // wave id = t-quarter
    const int b    = blockIdx.x;         // 0..1023
    const int half = b >> 9;             // channel half: 8*half..8*half+7
    const int pb   = b & 511;            // pixel-group id
    const int band = pb & 7;             // XCD id under modulo dispatch
    const int sub  = pb >> 3;            // 0..63 within band
    const int h = band * 16 + (sub >> 2);
    const int w = (sub & 3) * 64 + lane;
    const int pix = h * Wc + w;

    const float base_x = w * (2.0f / Wc) - 1.0f + 1.0f / Wc;
    const float base_y = h * (2.0f / Hc) - 1.0f + 1.0f / Hc;

    const unsigned short* __restrict__ imgTbH = imgTb + 8 * half;  // +16B
    const float* __restrict__ imgH = img + (size_t)(8 * half) * HWc;
    float* __restrict__ outH = out + (size_t)(8 * half) * HWc;

    switch (wv) {
        case 0:  run_quarter<0x8124u>(imgTbH, cum_flow, imgH, outH, wtab, pix, base_x, base_y); break; // {15,8,5,2}
        case 1:  run_quarter<0x4242u>(imgTbH, cum_flow, imgH, outH, wtab, pix, base_x, base_y); break; // {14,9,6,1}
        case 2:  run_quarter<0x2418u>(imgTbH, cum_flow, imgH, outH, wtab, pix, base_x, base_y); break; // {13,10,4,3}
        default: run_quarter<0x1881u>(imgTbH, cum_flow, imgH, outH, wtab, pix, base_x, base_y); break; // {12,11,7,0}
    }
}

// ---------------------------------------------------------------------------
// Fallback (Round-1 kernel): used only if ws_size is too small.
// ---------------------------------------------------------------------------
__global__ __launch_bounds__(256) void gridsample_warp_acc(
    const float* __restrict__ img, const float* __restrict__ cum_flow,
    const float* __restrict__ mask, const float* __restrict__ decay,
    float* __restrict__ out)
{
    const int w = threadIdx.x, h = blockIdx.x, t = blockIdx.y;
    const int pix = h * Wc + w;
    const float base_x = w * (2.0f / Wc) - 1.0f + 1.0f / Wc;
    const float base_y = h * (2.0f / Hc) - 1.0f + 1.0f / Hc;
    const float fxt = cum_flow[(t * 2 + 0) * HWc + pix];
    const float fyt = cum_flow[(t * 2 + 1) * HWc + pix];
    float acc[Cc];
#pragma unroll
    for (int c = 0; c < Cc; ++c) acc[c] = 0.0f;
    for (int k = 0; k <= t; ++k) {
        const float wkt = mask[t * Lc + k] * __expf(-DECAYc * decay[t * Lc + k]);
        const float fxk = cum_flow[(k * 2 + 0) * HWc + pix];
        const float fyk = cum_flow[(k * 2 + 1) * HWc + pix];
        float gx = base_x + (fxt - fxk);
        const float gy = base_y + (fyt - fyk);
        float m = gx + 1.0f;
        m -= 2.0f * floorf(m * 0.5f);
        gx = m - 1.0f;
        const float ix = (gx + 1.0f) * (Wc * 0.5f) - 0.5f;
        const float iy = (gy + 1.0f) * (Hc * 0.5f) - 0.5f;
        const float x0f = floorf(ix), y0f = floorf(iy);
        const float wx = ix - x0f, wy = iy - y0f;
        const int x0 = (int)x0f, y0 = (int)y0f;
        const int x0r = x0 & (Wc - 1), x1r = (x0 + 1) & (Wc - 1);
        const int y0c = min(max(y0, 0), Hc - 1), y1c = min(max(y0 + 1, 0), Hc - 1);
        const float a00 = wkt * (1.0f - wx) * (1.0f - wy);
        const float a01 = wkt * (1.0f - wx) * wy;
        const float a10 = wkt * wx * (1.0f - wy);
        const float a11 = wkt * wx * wy;
        const int o00 = y0c * Wc + x0r, o01 = y1c * Wc + x0r;
        const int o10 = y0c * Wc + x1r, o11 = y1c * Wc + x1r;
        const float* __restrict__ ik = img + (size_t)k * Cc * HWc;
#pragma unroll
        for (int c = 0; c < Cc; ++c) {
            const float* __restrict__ p = ik + c * HWc;
            acc[c] += p[o00] * a00 + p[o01] * a01 + p[o10] * a10 + p[o11] * a11;
        }
    }
    float* __restrict__ op = out + (size_t)t * Cc * HWc + pix;
#pragma unroll
    for (int c = 0; c < Cc; ++c) op[c * HWc] = acc[c];
}

extern "C" void kernel_launch(void* const* d_in, const int* in_sizes, int n_in,
                              void* d_out, int out_size, void* d_ws, size_t ws_size,
                              hipStream_t stream) {
    const float* img      = (const float*)d_in[0];
    const float* cum_flow = (const float*)d_in[1];
    const float* mask     = (const float*)d_in[2];
    const float* decay    = (const float*)d_in[3];
    float* out = (float*)d_out;

    const size_t needed = (size_t)Lc * HWc * Cc * sizeof(unsigned short);  // 16 MB
    if (ws_size >= needed) {
        unsigned short* imgTb = (unsigned short*)d_ws;
        transpose_cvt_bf16<<<dim3(512), 256, 0, stream>>>(img, imgTb);
        gridsample_bf16_q64<<<dim3(1024), 256, 0, stream>>>(
            imgTb, cum_flow, mask, decay, img, out);
    } else {
        dim3 grid(Hc, Lc, 1);
        gridsample_warp_acc<<<grid, Wc, 0, stream>>>(img, cum_flow, mask, decay, out);
    }
}